// Round 3
// baseline (75.854 us; speedup 1.0000x reference)
//
#include <hip/hip_runtime.h>

#define NROWS 8192
#define DDIM 64
#define HDIM 256
#define HPAD 264  // h row stride (ushort): 16 rows x 264

using bf16x8 = __attribute__((ext_vector_type(8))) short;
using f32x4  = __attribute__((ext_vector_type(4))) float;

__device__ __forceinline__ unsigned short f2bf(float x) {
    unsigned u = __float_as_uint(x);
    u += 0x7FFFu + ((u >> 16) & 1u);   // round-to-nearest-even
    return (unsigned short)(u >> 16);
}
__device__ __forceinline__ float fast_tanh(float x) {
    float e = __expf(2.0f * x);
    return 1.0f - 2.0f * __builtin_amdgcn_rcpf(e + 1.0f);
}

// Slim fused kernel: 16 rows/block, 256 threads (4 waves), 512 blocks.
// No weight staging in LDS: B-frags come straight from global (L1/L2-hot,
// 4 lines/instruction). LDS only for h round-trip + Sv + div partials (~10 KB).
__global__ __launch_bounds__(256)
void ode_slim(const float* __restrict__ t,
              const float* __restrict__ y,
              const float* __restrict__ W1,
              const float* __restrict__ b1,
              const float* __restrict__ wt,
              const float* __restrict__ W2,
              const float* __restrict__ b2,
              float* __restrict__ out) {
    const int tid  = threadIdx.x;
    const int w    = tid >> 6;     // wave 0..3
    const int lane = tid & 63;
    const int l16  = lane & 15;
    const int quad = lane >> 4;
    const int row0 = blockIdx.x * 16;

    __shared__ __align__(16) unsigned short h_lds[16 * HPAD]; // 8448 B
    __shared__ float svs[HDIM];                               // 1024 B
    __shared__ float dvp[64];                                 //  256 B

    // ---- A-frags from y (fp32 -> bf16). A[m=l16][k=quad*8+j]
    bf16x8 afr[2];
    {
        const float* yrow = y + (size_t)(row0 + l16) * DDIM;
        #pragma unroll
        for (int ks = 0; ks < 2; ++ks) {
            float4 f0 = *(const float4*)(yrow + ks * 32 + quad * 8);
            float4 f1 = *(const float4*)(yrow + ks * 32 + quad * 8 + 4);
            bf16x8 a;
            a[0]=(short)f2bf(f0.x); a[1]=(short)f2bf(f0.y); a[2]=(short)f2bf(f0.z); a[3]=(short)f2bf(f0.w);
            a[4]=(short)f2bf(f1.x); a[5]=(short)f2bf(f1.y); a[6]=(short)f2bf(f1.z); a[7]=(short)f2bf(f1.w);
            afr[ks] = a;
        }
    }

    // ---- phase-1 B-frags direct from global W1 [k][m] (4 lines/instruction)
    bf16x8 bfr1[4][2];
    #pragma unroll
    for (int ct = 0; ct < 4; ++ct) {
        const int m = w * 64 + ct * 16 + l16;
        #pragma unroll
        for (int ks = 0; ks < 2; ++ks) {
            const float* p = W1 + (size_t)(ks * 32 + quad * 8) * HDIM + m;
            bf16x8 b;
            #pragma unroll
            for (int j = 0; j < 8; ++j) b[j] = (short)f2bf(p[j * HDIM]);
            bfr1[ct][ks] = b;
        }
    }

    // ---- phase-2 B-frags direct from global W2 [k][n] (4 lines/instruction)
    const int ncol = w * 16 + l16;
    bf16x8 bfr2[8];
    #pragma unroll
    for (int ks = 0; ks < 8; ++ks) {
        const float* p = W2 + (size_t)(ks * 32 + quad * 8) * DDIM + ncol;
        bf16x8 b;
        #pragma unroll
        for (int j = 0; j < 8; ++j) b[j] = (short)f2bf(p[j * DDIM]);
        bfr2[ks] = b;
    }

    // ---- cooperative Sv: 4 lanes per W2 row, fp32 exact
    //      Sv[m] = sum_k W1[k][m] * W2[m][k]
    {
        const int g   = tid >> 2;   // 64 row-groups
        const int sub = tid & 3;    // lane within group
        #pragma unroll
        for (int it = 0; it < 4; ++it) {
            const int m = it * 64 + g;
            float part = 0.f;
            #pragma unroll
            for (int s = 0; s < 4; ++s) {
                const int k0 = s * 16 + sub * 4;
                float4 w2v = *(const float4*)(W2 + m * DDIM + k0);
                float a0 = W1[(k0 + 0) * HDIM + m];
                float a1 = W1[(k0 + 1) * HDIM + m];
                float a2 = W1[(k0 + 2) * HDIM + m];
                float a3 = W1[(k0 + 3) * HDIM + m];
                part += a0 * w2v.x + a1 * w2v.y + a2 * w2v.z + a3 * w2v.w;
            }
            part += __shfl_xor(part, 1);
            part += __shfl_xor(part, 2);
            if (sub == 0) svs[m] = part;
        }
    }

    // ---- small epilogue params
    const float ts = t[0];
    float cbv[4];
    #pragma unroll
    for (int ct = 0; ct < 4; ++ct) {
        int m = w * 64 + ct * 16 + l16;
        cbv[ct] = b1[m] + ts * wt[m];
    }
    const float b2v = b2[ncol];

    // ---- phase 1: z = y @ W1 (wave w -> H cols [w*64, w*64+64))
    f32x4 acc[4];
    #pragma unroll
    for (int ct = 0; ct < 4; ++ct) acc[ct] = (f32x4){0.f, 0.f, 0.f, 0.f};
    #pragma unroll
    for (int ct = 0; ct < 4; ++ct)
        #pragma unroll
        for (int ks = 0; ks < 2; ++ks)
            acc[ct] = __builtin_amdgcn_mfma_f32_16x16x32_bf16(afr[ks], bfr1[ct][ks], acc[ct], 0, 0, 0);

    __syncthreads();   // svs ready for all

    // ---- bias + tanh + divergence partials; h (bf16) -> LDS [row][m]
    float dv[4] = {0.f, 0.f, 0.f, 0.f};
    #pragma unroll
    for (int ct = 0; ct < 4; ++ct) {
        const int m = w * 64 + ct * 16 + l16;
        const float sv = svs[m];
        #pragma unroll
        for (int r = 0; r < 4; ++r) {            // C layout: col=l16, row=quad*4+r
            float z = acc[ct][r] + cbv[ct];
            float h = fast_tanh(z);
            dv[r] += (1.f - h * h) * sv;
            h_lds[(quad * 4 + r) * HPAD + m] = f2bf(h);
        }
    }
    #pragma unroll
    for (int off = 8; off; off >>= 1) {
        #pragma unroll
        for (int r = 0; r < 4; ++r) dv[r] += __shfl_down(dv[r], off, 16);
    }
    if (l16 == 0) {
        #pragma unroll
        for (int r = 0; r < 4; ++r) dvp[w * 16 + quad * 4 + r] = dv[r];
    }
    __syncthreads();

    // ---- phase 2: dy = h @ W2 (wave w -> output cols [w*16, w*16+16))
    f32x4 acc2 = (f32x4){0.f, 0.f, 0.f, 0.f};
    #pragma unroll
    for (int ks = 0; ks < 8; ++ks) {
        bf16x8 a = *(const bf16x8*)(&h_lds[l16 * HPAD + ks * 32 + quad * 8]);
        acc2 = __builtin_amdgcn_mfma_f32_16x16x32_bf16(a, bfr2[ks], acc2, 0, 0, 0);
    }
    #pragma unroll
    for (int r = 0; r < 4; ++r) {
        const int row = quad * 4 + r;
        out[(size_t)(row0 + row) * (DDIM + 1) + ncol] = acc2[r] + b2v;
    }

    // ---- divergence column (col 64)
    if (w == 0 && lane < 16) {
        float s = dvp[lane] + dvp[16 + lane] + dvp[32 + lane] + dvp[48 + lane];
        out[(size_t)(row0 + lane) * (DDIM + 1) + DDIM] = -s;
    }
}

extern "C" void kernel_launch(void* const* d_in, const int* in_sizes, int n_in,
                              void* d_out, int out_size, void* d_ws, size_t ws_size,
                              hipStream_t stream) {
    const float* t  = (const float*)d_in[0];
    const float* y  = (const float*)d_in[1];
    const float* W1 = (const float*)d_in[2];
    const float* b1 = (const float*)d_in[3];
    const float* wt = (const float*)d_in[4];
    const float* W2 = (const float*)d_in[5];
    const float* b2 = (const float*)d_in[6];
    float* out = (float*)d_out;

    ode_slim<<<NROWS / 16, 256, 0, stream>>>(t, y, W1, b1, wt, W2, b2, out);
}